// Round 14
// baseline (31.281 us; speedup 1.0000x reference)
//
#include <hip/hip_runtime.h>
#include <math.h>

// Problem constants (reference: B,D,E,H = 4,128,512,512)
#define BATCH 4
#define DDIM  128
#define EDIM  512
#define HDIM  512

// c = 2*log2(e): P=exp2(c*dec_t), Q=exp2(c*enc_t) so e^{2(dec+enc)} = P*Q
#define TANH_SCALE 2.8853900817779268f

typedef short short8v __attribute__((ext_vector_type(8)));
typedef float f32x4   __attribute__((ext_vector_type(4)));
typedef float f32x2   __attribute__((ext_vector_type(2)));

#define EXP2F(x) __builtin_amdgcn_exp2f(x)
#define RCPF(x)  __builtin_amdgcn_rcpf(x)

// fp32 -> bf16 bits, round-to-nearest-even
static __device__ inline unsigned short f2bf(float f) {
    unsigned u = __float_as_uint(f);
    return (unsigned short)((u + 0x7FFFu + ((u >> 16) & 1u)) >> 16);
}
// pack two fp32 -> one u32 {bf16(f1):bf16(f0)}
static __device__ inline unsigned pack_bf2(float f0, float f1) {
    unsigned u0 = __float_as_uint(f0), u1 = __float_as_uint(f1);
    u0 += 0x7FFFu + ((u0 >> 16) & 1u);
    u1 += 0x7FFFu + ((u1 >> 16) & 1u);
    return __builtin_amdgcn_perm(u1, u0, 0x07060302u);
}
// bf16 bits -> fp32
static __device__ inline float bf2f(unsigned short h) {
    return __uint_as_float(((unsigned)h) << 16);
}
static __device__ inline float blo(unsigned u) { return __uint_as_float(u << 16); }
static __device__ inline float bhi(unsigned u) { return __uint_as_float(u & 0xffff0000u); }

// ---------------------------------------------------------------------------
// bf16 MFMA GEMM pair (NT), 2-phase pipeline — UNCHANGED from R10/R13.
// ---------------------------------------------------------------------------
__global__ __launch_bounds__(256)
void gemm_both(const float* __restrict__ xdec, const float* __restrict__ W2,
               const float* __restrict__ xenc, const float* __restrict__ W1,
               unsigned short* __restrict__ P, unsigned short* __restrict__ Q) {
    __shared__ unsigned short As[2][64][40];   // 10 KB (dbuf, 80B rows)
    __shared__ unsigned short Bs[2][64][40];   // 10 KB

    const int id = blockIdx.x;
    const float *Ab, *Bb;
    unsigned short* Cb;
    int m0, n0;
    if (id < 64) {                 // dec: 4b x 2m(d) x 8n(h)
        int b = id >> 4, r = id & 15;
        m0 = (r >> 3) * 64; n0 = (r & 7) * 64;
        Ab = xdec + (long)b * DDIM * HDIM;
        Bb = W2;
        Cb = P + (long)b * DDIM * HDIM;
    } else {                       // enc: 4b x 8m(h) x 8n(e)
        int t2 = id - 64;
        int b = t2 >> 6, r = t2 & 63;
        m0 = (r >> 3) * 64; n0 = (r & 7) * 64;
        Ab = W1;
        Bb = xenc + (long)b * EDIM * HDIM;
        Cb = Q + (long)b * HDIM * EDIM;
    }

    const int t    = threadIdx.x;
    const int srow = t >> 2;            // 0..63: staged row
    const int skq  = (t & 3) << 3;      // 0,8,16,24: k-offset (8 elems)

    const int wid = t >> 6, wm = wid >> 1, wn = wid & 1;
    const int l   = t & 63, lr = l & 15, c16 = l >> 4;

    f32x4 acc[2][2] = {};

    const float* ap = Ab + (long)(m0 + srow) * HDIM + skq;
    const float* bp = Bb + (long)(n0 + srow) * HDIM + skq;

    float4 a0 = *(const float4*)ap, a1 = *(const float4*)(ap + 4);
    float4 b0 = *(const float4*)bp, b1 = *(const float4*)(bp + 4);

    int cur = 0;
    for (int k0 = 0; k0 < HDIM; k0 += 32) {
        uint4 apk, bpk;
        apk.x = pack_bf2(a0.x, a0.y); apk.y = pack_bf2(a0.z, a0.w);
        apk.z = pack_bf2(a1.x, a1.y); apk.w = pack_bf2(a1.z, a1.w);
        bpk.x = pack_bf2(b0.x, b0.y); bpk.y = pack_bf2(b0.z, b0.w);
        bpk.z = pack_bf2(b1.x, b1.y); bpk.w = pack_bf2(b1.z, b1.w);
        *(uint4*)&As[cur][srow][skq] = apk;
        *(uint4*)&Bs[cur][srow][skq] = bpk;

        if (k0 + 32 < HDIM) {
            ap += 32; bp += 32;
            a0 = *(const float4*)ap; a1 = *(const float4*)(ap + 4);
            b0 = *(const float4*)bp; b1 = *(const float4*)(bp + 4);
        }

        asm volatile("s_waitcnt lgkmcnt(0)" ::: "memory");
        __builtin_amdgcn_s_barrier();
        __builtin_amdgcn_sched_barrier(0);

        short8v af[2], bf[2];
        #pragma unroll
        for (int fm = 0; fm < 2; ++fm)
            af[fm] = *(const short8v*)&As[cur][wm * 32 + fm * 16 + lr][c16 * 8];
        #pragma unroll
        for (int fn = 0; fn < 2; ++fn)
            bf[fn] = *(const short8v*)&Bs[cur][wn * 32 + fn * 16 + lr][c16 * 8];
        #pragma unroll
        for (int fm = 0; fm < 2; ++fm)
            #pragma unroll
            for (int fn = 0; fn < 2; ++fn)
                acc[fm][fn] = __builtin_amdgcn_mfma_f32_16x16x32_bf16(
                    af[fm], bf[fn], acc[fm][fn], 0, 0, 0);
        cur ^= 1;
    }

    const int crow = c16 << 2;
    #pragma unroll
    for (int fm = 0; fm < 2; ++fm)
        #pragma unroll
        for (int fn = 0; fn < 2; ++fn)
            #pragma unroll
            for (int r = 0; r < 4; ++r) {
                int rr = m0 + wm * 32 + fm * 16 + crow + r;
                int cc = n0 + wn * 32 + fn * 16 + lr;
                Cb[(long)rr * 512 + cc] = f2bf(EXP2F(TANH_SCALE * acc[fm][fn][r]));
            }
}

// ---------------------------------------------------------------------------
// MERGED attn + log_softmax, v2: 4h QUAD-COMBINE + uint4 loads.
// 256 blocks (1/CU), 1024 threads = 64 e-octs(8e) x 16 h-groups(32h) =
// 16 waves (wave == h-group -> combo reads are wave-broadcast).
//   sum_i a_i/x_i over 4 h's: n=(n1*d2+n2*d1), den=d1*d2, ONE rcp per 4h
//   (13 pk + 2 rcp + 2 fma per 4h x 2e x 1d  ->  5.75 cy/elem vs 7.5).
// Loads: 4 x uint4 (8 e's) per 4h -> half the VMEM instructions of R13.
// Reduce: transposed lds_red[j][hg][ei] -> conflict-free writes.
// ---------------------------------------------------------------------------
__global__ __launch_bounds__(1024)
void attn_lsm(const unsigned short* __restrict__ P,    // (B,D,H) bf16 exp2
              const unsigned short* __restrict__ Q,    // (B,H,E) bf16 exp2
              const unsigned char* __restrict__ mask,  // (B,E)
              const float* __restrict__ vw,            // (H)
              float* __restrict__ out) {               // (B,D,E)
    const int g    = blockIdx.x;            // 0..255
    const int xcd  = g & 7;
    const int b    = xcd & 3;
    const int dp   = (g >> 3) + ((xcd >> 2) << 5);     // 0..63
    const int pair = b * 64 + dp;           // 0..255
    const int bd0  = pair * 2;
    const int t    = threadIdx.x;           // 0..1023
    const int eq   = t & 63;                // e-oct (8 e's each)
    const int hg   = t >> 6;                // h-group 0..15 (32 h each) == wave

    __shared__ f32x2 combo2[256][3];        // per h-pair {P0pr,P1pr,(a,b)} 6KB
    __shared__ float lds_red[16][16][64];   // [j][hg][ei] 64KB
    __shared__ float red[16];

    if (t < 256) {
        int h = t * 2;
        f32x2 p0, p1, vv;
        p0.x = bf2f(P[bd0 * HDIM + h]);       p0.y = bf2f(P[bd0 * HDIM + h + 1]);
        p1.x = bf2f(P[(bd0 + 1) * HDIM + h]); p1.y = bf2f(P[(bd0 + 1) * HDIM + h + 1]);
        vv.x = -2.0f * vw[h];                 vv.y = -2.0f * vw[h + 1];
        combo2[t][0] = p0; combo2[t][1] = p1; combo2[t][2] = vv;
    }
    __syncthreads();

    const unsigned short* qb = Q + b * HDIM * EDIM + (hg * 32) * EDIM + eq * 8;
    f32x2 acc2[2][4] = {};                  // [d][e-pair]
    f32x2 ones; ones.x = 1.0f; ones.y = 1.0f;

    // one QUAD: (4h, e-pair, 1d) -> 13 pk + 2 rcp + 2 fma
#define QUAD(P01, P23, VV01, VV23, q0, q1, q2, q3, accp)                        \
    {                                                                           \
        f32x2 x0, x1, x2, x3, d1, d2, t1, n1, t2, n2, nn, n, den;               \
        asm("v_pk_fma_f32 %0, %1, %2, %3 op_sel_hi:[0,1,1]"                     \
            : "=v"(x0) : "v"(P01), "v"(q0), "v"(ones));                         \
        asm("v_pk_fma_f32 %0, %1, %2, %3 op_sel:[1,0,0] op_sel_hi:[1,1,1]"      \
            : "=v"(x1) : "v"(P01), "v"(q1), "v"(ones));                         \
        asm("v_pk_fma_f32 %0, %1, %2, %3 op_sel_hi:[0,1,1]"                     \
            : "=v"(x2) : "v"(P23), "v"(q2), "v"(ones));                         \
        asm("v_pk_fma_f32 %0, %1, %2, %3 op_sel:[1,0,0] op_sel_hi:[1,1,1]"      \
            : "=v"(x3) : "v"(P23), "v"(q3), "v"(ones));                         \
        asm("v_pk_mul_f32 %0, %1, %2" : "=v"(d1) : "v"(x0), "v"(x1));           \
        asm("v_pk_mul_f32 %0, %1, %2" : "=v"(d2) : "v"(x2), "v"(x3));           \
        asm("v_pk_mul_f32 %0, %1, %2 op_sel:[1,0] op_sel_hi:[1,1]"              \
            : "=v"(t1) : "v"(VV01), "v"(x0));                                   \
        asm("v_pk_fma_f32 %0, %1, %2, %3 op_sel_hi:[0,1,1]"                     \
            : "=v"(n1) : "v"(VV01), "v"(x1), "v"(t1));                          \
        asm("v_pk_mul_f32 %0, %1, %2 op_sel:[1,0] op_sel_hi:[1,1]"              \
            : "=v"(t2) : "v"(VV23), "v"(x2));                                   \
        asm("v_pk_fma_f32 %0, %1, %2, %3 op_sel_hi:[0,1,1]"                     \
            : "=v"(n2) : "v"(VV23), "v"(x3), "v"(t2));                          \
        asm("v_pk_mul_f32 %0, %1, %2" : "=v"(nn) : "v"(n1), "v"(d2));           \
        asm("v_pk_fma_f32 %0, %1, %2, %3" : "=v"(n) : "v"(n2), "v"(d1), "v"(nn));\
        asm("v_pk_mul_f32 %0, %1, %2" : "=v"(den) : "v"(d1), "v"(d2));          \
        accp.x = fmaf(n.x, RCPF(den.x), accp.x);                                \
        accp.y = fmaf(n.y, RCPF(den.y), accp.y);                                \
    }

    #pragma unroll 2
    for (int k = 0; k < 8; ++k) {           // 8 quads x 4h = 32 h
        uint4 r0 = *(const uint4*)(qb + (size_t)(k * 4 + 0) * EDIM);
        uint4 r1 = *(const uint4*)(qb + (size_t)(k * 4 + 1) * EDIM);
        uint4 r2 = *(const uint4*)(qb + (size_t)(k * 4 + 2) * EDIM);
        uint4 r3 = *(const uint4*)(qb + (size_t)(k * 4 + 3) * EDIM);

        f32x2 qr[4][4];                     // [h-row][e-pair]
        qr[0][0].x = blo(r0.x); qr[0][0].y = bhi(r0.x);
        qr[0][1].x = blo(r0.y); qr[0][1].y = bhi(r0.y);
        qr[0][2].x = blo(r0.z); qr[0][2].y = bhi(r0.z);
        qr[0][3].x = blo(r0.w); qr[0][3].y = bhi(r0.w);
        qr[1][0].x = blo(r1.x); qr[1][0].y = bhi(r1.x);
        qr[1][1].x = blo(r1.y); qr[1][1].y = bhi(r1.y);
        qr[1][2].x = blo(r1.z); qr[1][2].y = bhi(r1.z);
        qr[1][3].x = blo(r1.w); qr[1][3].y = bhi(r1.w);
        qr[2][0].x = blo(r2.x); qr[2][0].y = bhi(r2.x);
        qr[2][1].x = blo(r2.y); qr[2][1].y = bhi(r2.y);
        qr[2][2].x = blo(r2.z); qr[2][2].y = bhi(r2.z);
        qr[2][3].x = blo(r2.w); qr[2][3].y = bhi(r2.w);
        qr[3][0].x = blo(r3.x); qr[3][0].y = bhi(r3.x);
        qr[3][1].x = blo(r3.y); qr[3][1].y = bhi(r3.y);
        qr[3][2].x = blo(r3.z); qr[3][2].y = bhi(r3.z);
        qr[3][3].x = blo(r3.w); qr[3][3].y = bhi(r3.w);

        const int hp0 = hg * 16 + k * 2;    // h-pair indices (h0,h1),(h2,h3)
        f32x2 P01d0 = combo2[hp0][0],     P23d0 = combo2[hp0 + 1][0];
        f32x2 P01d1 = combo2[hp0][1],     P23d1 = combo2[hp0 + 1][1];
        f32x2 VV01  = combo2[hp0][2],     VV23  = combo2[hp0 + 1][2];

        #pragma unroll
        for (int ep = 0; ep < 4; ++ep) {
            QUAD(P01d0, P23d0, VV01, VV23,
                 qr[0][ep], qr[1][ep], qr[2][ep], qr[3][ep], acc2[0][ep]);
            QUAD(P01d1, P23d1, VV01, VV23,
                 qr[0][ep], qr[1][ep], qr[2][ep], qr[3][ep], acc2[1][ep]);
        }
    }
#undef QUAD

    // store 16 partials: j = d*8 + e-within-oct; conflict-free writes
    #pragma unroll
    for (int d = 0; d < 2; ++d)
        #pragma unroll
        for (int ep = 0; ep < 4; ++ep) {
            lds_red[d * 8 + ep * 2 + 0][hg][eq] = acc2[d][ep].x;
            lds_red[d * 8 + ep * 2 + 1][hg][eq] = acc2[d][ep].y;
        }
    __syncthreads();

    // thread t owns output (d = t>>9, e = t&511); 16-way h-group reduce
    const int d = t >> 9, e = t & 511;
    const int ei = e >> 3, j = d * 8 + (e & 7);
    float acc = (((lds_red[j][0][ei]  + lds_red[j][1][ei]) +
                  (lds_red[j][2][ei]  + lds_red[j][3][ei])) +
                 ((lds_red[j][4][ei]  + lds_red[j][5][ei]) +
                  (lds_red[j][6][ei]  + lds_red[j][7][ei]))) +
                (((lds_red[j][8][ei]  + lds_red[j][9][ei]) +
                  (lds_red[j][10][ei] + lds_red[j][11][ei])) +
                 ((lds_red[j][12][ei] + lds_red[j][13][ei]) +
                  (lds_red[j][14][ei] + lds_red[j][15][ei])));

    const bool mk = mask[b * EDIM + e];
    float val = mk ? -INFINITY : acc;

    // --- masked log_softmax: waves 0..7 = d0, waves 8..15 = d1 ---
    const int wv = t >> 6, lid = t & 63, dg8 = d * 8;

    float m = val;
    #pragma unroll
    for (int o = 32; o >= 1; o >>= 1) m = fmaxf(m, __shfl_xor(m, o));
    if (lid == 0) red[wv] = m;
    __syncthreads();
    m = red[dg8];
    #pragma unroll
    for (int i = 1; i < 8; ++i) m = fmaxf(m, red[dg8 + i]);
    __syncthreads();

    float s = __expf(val - m);
    #pragma unroll
    for (int o = 32; o >= 1; o >>= 1) s += __shfl_xor(s, o);
    if (lid == 0) red[wv] = s;
    __syncthreads();
    float tot = 0.f;
    #pragma unroll
    for (int i = 0; i < 8; ++i) tot += red[dg8 + i];

    out[(long)(bd0 + d) * EDIM + e] = val - m - __logf(tot);
}

// ---------------------------------------------------------------------------
extern "C" void kernel_launch(void* const* d_in, const int* in_sizes, int n_in,
                              void* d_out, int out_size, void* d_ws, size_t ws_size,
                              hipStream_t stream) {
    const float*         xdec = (const float*)d_in[0];         // (B,D,H)
    const float*         xenc = (const float*)d_in[1];         // (B,E,H)
    const unsigned char* mask = (const unsigned char*)d_in[2]; // (B,E)
    const float*         W1   = (const float*)d_in[3];         // (H,H)
    const float*         W2   = (const float*)d_in[4];         // (H,H)
    const float*         vw   = (const float*)d_in[5];         // (H)
    float*               out  = (float*)d_out;                 // (B,D,E)

    unsigned short* P = (unsigned short*)d_ws;                 // 262144 bf16 (512 KB)
    unsigned short* Q = P + 262144;                            // 1048576 bf16 (2 MB)

    gemm_both<<<320, 256, 0, stream>>>(xdec, W2, xenc, W1, P, Q);
    attn_lsm<<<256, 1024, 0, stream>>>(P, Q, mask, vw, out);
}